// Round 2
// baseline (2717.282 us; speedup 1.0000x reference)
//
#include <hip/hip_runtime.h>

#define DEV static __device__ __forceinline__

constexpr int Bc = 2, Tc = 128, Nc = 1024, Fc = 128, Hc = 4, Rc = 32, Dc = 32;
constexpr int NF  = Nc * Fc;        // 131072 = 2^17
constexpr int TOK = Bc * Tc * Nc;   // 262144
constexpr float EPSc = 1e-6f;
constexpr float RSD  = 0.17677669529663687f;  // 1/sqrt(32)

DEV unsigned short f2bu(float f) {              // fp32 -> bf16 (RNE)
    unsigned u = __builtin_bit_cast(unsigned, f);
    u += 0x7fffu + ((u >> 16) & 1u);
    return (unsigned short)(u >> 16);
}
DEV float bu2f(unsigned short s) {
    return __builtin_bit_cast(float, ((unsigned)s) << 16);
}
DEV float sigmoidf_(float z) { return 1.f / (1.f + __expf(-z)); }
DEV void fma4(float4& a, float s, const float4& b) {
    a.x = fmaf(s, b.x, a.x); a.y = fmaf(s, b.y, a.y);
    a.z = fmaf(s, b.z, a.z); a.w = fmaf(s, b.w, a.w);
}

// ---------------- K1/K5: rmsnorm-over-t scale factors -----------------
__global__ void k_rms_f32(const float* __restrict__ x, float* __restrict__ inv) {
    int j = blockIdx.x * 256 + threadIdx.x;     // j = b*NF + p
    int b = j >> 17;
    int p = j & (NF - 1);
    const float* px = x + (size_t)b * Tc * NF + p;
    float s = 0.f;
#pragma unroll 8
    for (int t = 0; t < Tc; ++t) { float v = px[(size_t)t * NF]; s = fmaf(v, v, s); }
    inv[j] = rsqrtf(s * (1.f / Tc) + EPSc);
}

__global__ void k_rms_bf16(const unsigned short* __restrict__ xb, float* __restrict__ inv) {
    int j = blockIdx.x * 256 + threadIdx.x;
    int b = j >> 17;
    int p = j & (NF - 1);
    const unsigned short* px = xb + (size_t)b * Tc * NF + p;
    float s = 0.f;
#pragma unroll 8
    for (int t = 0; t < Tc; ++t) { float v = bu2f(px[(size_t)t * NF]); s = fmaf(v, v, s); }
    inv[j] = rsqrtf(s * (1.f / Tc) + EPSc);
}

// ---------------- K2: q/v projection + attention logits ----------------
// block = 256 threads, 64 tokens. 4 output-chunks of 64 (q0,q1,v0,v1).
__global__ __launch_bounds__(256, 1) void k_proj(
    const float* __restrict__ x, const float* __restrict__ inv1, const float* __restrict__ nw,
    const float* __restrict__ q_w, const float* __restrict__ q_b,
    const float* __restrict__ v_w, const float* __restrict__ v_b,
    const float* __restrict__ key_p,
    unsigned short* __restrict__ Lb, unsigned short* __restrict__ XVb)
{
    __shared__ float s_xn[128][68];     // [c][tok]   (68: 16B-aligned pad)
    __shared__ float s_wc[128][68];     // [c][j]
    __shared__ float s_q [64][132];     // [tok][o]   (132: bank pad)
    __shared__ float s_kp[4][32][32];   // [h][d][r], pre-scaled by 1/sqrt(32)
    int tid = threadIdx.x;
    int tk0 = blockIdx.x * 64;

    for (int i = tid; i < 4096; i += 256) {
        int r = i >> 7; int rem = i & 127; int h = rem >> 5; int d = rem & 31;
        s_kp[h][d][r] = key_p[i] * RSD;
    }
    for (int i = tid; i < 8192; i += 256) {
        int tt = i >> 7; int c = i & 127;
        int tk = tk0 + tt;
        int b = tk >> 17; int n = tk & (Nc - 1);
        s_xn[c][tt] = x[(size_t)tk * 128 + c] * inv1[(size_t)b * NF + n * 128 + c] * nw[c];
    }
    __syncthreads();

    int ttk = tid & 15, to = tid >> 4;
    for (int chunk = 0; chunk < 4; ++chunk) {
        const float* W  = (chunk < 2) ? q_w : v_w;
        const float* Bv = (chunk < 2) ? q_b : v_b;
        int wbase = (chunk & 1) * 64;
        for (int i = tid; i < 8192; i += 256) {
            int j = i >> 7; int c = i & 127;
            s_wc[c][j] = W[(size_t)(wbase + j) * 128 + c];
        }
        __syncthreads();
        float acc[4][4];
#pragma unroll
        for (int j2 = 0; j2 < 4; j2++) {
            float bb = Bv[wbase + to * 4 + j2];
            acc[0][j2] = bb; acc[1][j2] = bb; acc[2][j2] = bb; acc[3][j2] = bb;
        }
        for (int c = 0; c < 128; ++c) {
            float4 xa = *(const float4*)&s_xn[c][ttk * 4];
            float4 wa = *(const float4*)&s_wc[c][to * 4];
            float xs[4] = {xa.x, xa.y, xa.z, xa.w};
            float wv[4] = {wa.x, wa.y, wa.z, wa.w};
#pragma unroll
            for (int i2 = 0; i2 < 4; i2++)
#pragma unroll
                for (int j2 = 0; j2 < 4; j2++)
                    acc[i2][j2] = fmaf(xs[i2], wv[j2], acc[i2][j2]);
        }
        int olocal = wbase + to * 4;
        if (chunk < 2) {
#pragma unroll
            for (int i2 = 0; i2 < 4; i2++) {
                int tok = ttk * 4 + i2;
#pragma unroll
                for (int j2 = 0; j2 < 4; j2++) s_q[tok][olocal + j2] = acc[i2][j2];
            }
        } else {
#pragma unroll
            for (int i2 = 0; i2 < 4; i2++) {
                int tk = tk0 + ttk * 4 + i2;
                ushort4 pk;
                pk.x = f2bu(acc[i2][0]); pk.y = f2bu(acc[i2][1]);
                pk.z = f2bu(acc[i2][2]); pk.w = f2bu(acc[i2][3]);
                *(ushort4*)&XVb[(size_t)tk * 128 + olocal] = pk;
            }
        }
        __syncthreads();
    }

    // attention logits L[tok][h*32+r] = sum_d q[h,d]*kp[h][d][r]
#pragma unroll
    for (int pass = 0; pass < 2; ++pass) {
        int hr0 = pass * 64 + (tid >> 4) * 4;
        int h = hr0 >> 5, r0 = hr0 & 31;
        int tq = tid & 15;
        float a[4][4];
#pragma unroll
        for (int i2 = 0; i2 < 4; i2++) { a[i2][0] = 0; a[i2][1] = 0; a[i2][2] = 0; a[i2][3] = 0; }
        for (int d = 0; d < 32; ++d) {
            float4 kv = *(const float4*)&s_kp[h][d][r0];
            float kk[4] = {kv.x, kv.y, kv.z, kv.w};
#pragma unroll
            for (int i2 = 0; i2 < 4; i2++) {
                float qv = s_q[tq * 4 + i2][h * 32 + d];
#pragma unroll
                for (int j2 = 0; j2 < 4; j2++) a[i2][j2] = fmaf(qv, kk[j2], a[i2][j2]);
            }
        }
#pragma unroll
        for (int i2 = 0; i2 < 4; i2++) {
            int tk = tk0 + tq * 4 + i2;
            ushort4 pk;
            pk.x = f2bu(a[i2][0]); pk.y = f2bu(a[i2][1]);
            pk.z = f2bu(a[i2][2]); pk.w = f2bu(a[i2][3]);
            *(ushort4*)&Lb[(size_t)tk * 128 + h * 32 + r0] = pk;
        }
    }
}

// ---------------- K3: landmark aggregation + n-softmax stats ----------------
// block = (bt,h); computes VL[h,r,d] = sum_n softmax_r(L)[n,r]*xv[n,d], and
// per (h,r): max_n L, sum_n exp(L-max)  (online).
__global__ void k_land(const unsigned short* __restrict__ Lb, const unsigned short* __restrict__ XVb,
                       float* __restrict__ VL, float* __restrict__ M2, float* __restrict__ S2)
{
    __shared__ float sL [64][33];
    __shared__ float sXV[64][36];
    int tid = threadIdx.x;
    int blk = blockIdx.x;               // bt*4 + h
    int h = blk & 3; int bt = blk >> 2;
    size_t base = (size_t)bt * Nc * 128 + h * 32;
    int r_acc = tid >> 3, d0 = (tid & 7) * 4;
    float a0 = 0, a1 = 0, a2 = 0, a3 = 0;
    float m_run = -1e30f, s_run = 0.f;
    for (int n0 = 0; n0 < Nc; n0 += 64) {
        for (int k = tid; k < 2048; k += 256) {
            int i = k >> 5, rr = k & 31;
            size_t g = base + (size_t)(n0 + i) * 128 + rr;
            sL [i][rr] = bu2f(Lb [g]);
            sXV[i][rr] = bu2f(XVb[g]);
        }
        __syncthreads();
        if (tid < 32) {                  // online n-softmax stats, r = tid
            float m = m_run, s = s_run;
#pragma unroll 4
            for (int i = 0; i < 64; i++) {
                float v = sL[i][tid];
                float mn = fmaxf(m, v);
                s = s * __expf(m - mn) + __expf(v - mn);
                m = mn;
            }
            m_run = m; s_run = s;
        }
        __syncthreads();
        if (tid < 64) {                  // p1 = softmax over r, in place
            float mx = -1e30f;
#pragma unroll 4
            for (int rr = 0; rr < 32; rr++) mx = fmaxf(mx, sL[tid][rr]);
            float sm = 0.f;
#pragma unroll 4
            for (int rr = 0; rr < 32; rr++) { float e = __expf(sL[tid][rr] - mx); sL[tid][rr] = e; sm += e; }
            float iv = 1.f / sm;
#pragma unroll 4
            for (int rr = 0; rr < 32; rr++) sL[tid][rr] *= iv;
        }
        __syncthreads();
#pragma unroll 2
        for (int i = 0; i < 64; i++) {
            float p = sL[i][r_acc];
            float4 v = *(const float4*)&sXV[i][d0];
            a0 = fmaf(p, v.x, a0); a1 = fmaf(p, v.y, a1);
            a2 = fmaf(p, v.z, a2); a3 = fmaf(p, v.w, a3);
        }
        __syncthreads();
    }
    *(float4*)&VL[((size_t)blk * 32 + r_acc) * 32 + d0] = make_float4(a0, a1, a2, a3);
    if (tid < 32) { M2[blk * 32 + tid] = m_run; S2[blk * 32 + tid] = s_run; }
}

// ---------------- K4: scatter landmarks + gates + first residual ----------------
__global__ void k_out1(const float* __restrict__ x,
                       const unsigned short* __restrict__ Lb, const unsigned short* __restrict__ XVb,
                       const float* __restrict__ VL, const float* __restrict__ M2, const float* __restrict__ S2,
                       const float* __restrict__ alpha, const float* __restrict__ beta,
                       unsigned short* __restrict__ X2b)
{
    __shared__ float sVL[128][32];      // [h*32+r][d]
    __shared__ float sP[8][128];        // p2 per token
    __shared__ float sM[128], sSi[128], sAB[8];
    int tid = threadIdx.x;
    int tk0 = blockIdx.x * 8;
    int bt = tk0 >> 10;
    for (int k = tid; k < 4096; k += 256) sVL[k >> 5][k & 31] = VL[(size_t)bt * 4096 + k];
    if (tid < 128) { sM[tid] = M2[bt * 128 + tid]; sSi[tid] = 1.f / S2[bt * 128 + tid]; }
    if (tid < 8)   sAB[tid] = (tid < 4) ? sigmoidf_(alpha[tid]) : sigmoidf_(beta[tid - 4]);
    __syncthreads();
    for (int k = tid; k < 1024; k += 256) {
        int ti = k >> 7, f = k & 127;
        float lv = bu2f(Lb[(size_t)(tk0 + ti) * 128 + f]);
        sP[ti][f] = __expf(lv - sM[f]) * sSi[f];
    }
    __syncthreads();
    int ti = tid >> 5, quad = tid & 31;
    int h = quad >> 3, d0 = (quad & 7) * 4;
    float a0 = 0, a1 = 0, a2 = 0, a3 = 0;
    int hr0 = h * 32;
#pragma unroll 4
    for (int r = 0; r < 32; ++r) {
        float p = sP[ti][hr0 + r];
        float4 v = *(const float4*)&sVL[hr0 + r][d0];
        a0 = fmaf(p, v.x, a0); a1 = fmaf(p, v.y, a1);
        a2 = fmaf(p, v.z, a2); a3 = fmaf(p, v.w, a3);
    }
    size_t gi = (size_t)(tk0 + ti) * 128 + quad * 4;   // f0 = h*32+d0 = quad*4
    ushort4 xv4 = *(const ushort4*)&XVb[gi];
    float sa = sAB[h], sb = sAB[4 + h];
    float o0 = fmaf(sb, a0, fmaf(sa, bu2f(xv4.x), x[gi + 0]));
    float o1 = fmaf(sb, a1, fmaf(sa, bu2f(xv4.y), x[gi + 1]));
    float o2 = fmaf(sb, a2, fmaf(sa, bu2f(xv4.z), x[gi + 2]));
    float o3 = fmaf(sb, a3, fmaf(sa, bu2f(xv4.w), x[gi + 3]));
    ushort4 pk; pk.x = f2bu(o0); pk.y = f2bu(o1); pk.z = f2bu(o2); pk.w = f2bu(o3);
    *(ushort4*)&X2b[gi] = pk;
}

// ---------------- K6: fused FFN over the t axis + final residual ----------------
// block = (b,n): full 128(t) x 128(f) tile in LDS; o-chunks of 32.
__global__ __launch_bounds__(256, 1) void k_ffn(
    const unsigned short* __restrict__ X2b, const float* __restrict__ inv2, const float* __restrict__ nw,
    const float* __restrict__ w1, const float* __restrict__ b1,
    const float* __restrict__ w2, const float* __restrict__ b2,
    const float* __restrict__ w3, const float* __restrict__ b3,
    float* __restrict__ out)
{
    __shared__ float xt [128][128];   // [c(=t)][f]
    __shared__ float gb [32][128];    // [j][f]
    __shared__ float w1c[128][36];    // [c][j]
    __shared__ float w2c[128][36];
    __shared__ float w3c[32][136];    // [j][t]
    __shared__ float sscale[128];
    int tid = threadIdx.x;
    int blk = blockIdx.x;             // b*N + n
    int b = blk >> 10, n = blk & 1023;
    if (tid < 128) sscale[tid] = inv2[(size_t)blk * 128 + tid] * nw[tid];
    __syncthreads();
    for (int k = tid; k < 16384; k += 256) {
        int t = k >> 7, f = k & 127;
        xt[t][f] = bu2f(X2b[((size_t)(b * Tc + t) * Nc + n) * 128 + f]) * sscale[f];
    }
    int tf = tid & 31, to = tid >> 5;    // g-phase: f0 = tf*4, o0 = to*4 (32 o per chunk)
    int f0 = tf * 4, o0 = to * 4;
    int tq = to;                         // acc-phase: t-range = tq*16 .. +15
    float4 oacc[16];
#pragma unroll
    for (int i = 0; i < 16; i++) oacc[i] = make_float4(0, 0, 0, 0);
    __syncthreads();

    for (int oc = 0; oc < 512; oc += 32) {
        for (int k = tid; k < 4096; k += 256) {
            int j = k >> 7, c = k & 127;
            w1c[c][j] = w1[(size_t)(oc + j) * 128 + c];
            w2c[c][j] = w2[(size_t)(oc + j) * 128 + c];
        }
        for (int k = tid; k < 4096; k += 256) {
            int t = k >> 5, j = k & 31;
            w3c[j][t] = w3[(size_t)t * 512 + oc + j];
        }
        __syncthreads();
        // ---- g = silu(w1@xn2 + b1) * (w2@xn2 + b2), 4f x 4o per thread ----
        float h1a[4][4], h2a[4][4];
#pragma unroll
        for (int j2 = 0; j2 < 4; j2++) {
            float bb1 = b1[oc + o0 + j2], bb2 = b2[oc + o0 + j2];
            h1a[0][j2] = bb1; h1a[1][j2] = bb1; h1a[2][j2] = bb1; h1a[3][j2] = bb1;
            h2a[0][j2] = bb2; h2a[1][j2] = bb2; h2a[2][j2] = bb2; h2a[3][j2] = bb2;
        }
        for (int c = 0; c < 128; ++c) {
            float4 xv4 = *(const float4*)&xt[c][f0];
            float4 w1v = *(const float4*)&w1c[c][o0];
            float4 w2v = *(const float4*)&w2c[c][o0];
            float xs[4] = {xv4.x, xv4.y, xv4.z, xv4.w};
            float u1[4] = {w1v.x, w1v.y, w1v.z, w1v.w};
            float u2[4] = {w2v.x, w2v.y, w2v.z, w2v.w};
#pragma unroll
            for (int fi = 0; fi < 4; fi++)
#pragma unroll
                for (int j2 = 0; j2 < 4; j2++) {
                    h1a[fi][j2] = fmaf(xs[fi], u1[j2], h1a[fi][j2]);
                    h2a[fi][j2] = fmaf(xs[fi], u2[j2], h2a[fi][j2]);
                }
        }
#pragma unroll
        for (int j2 = 0; j2 < 4; j2++) {
            float4 gv; float z;
            z = h1a[0][j2]; gv.x = z * sigmoidf_(z) * h2a[0][j2];
            z = h1a[1][j2]; gv.y = z * sigmoidf_(z) * h2a[1][j2];
            z = h1a[2][j2]; gv.z = z * sigmoidf_(z) * h2a[2][j2];
            z = h1a[3][j2]; gv.w = z * sigmoidf_(z) * h2a[3][j2];
            *(float4*)&gb[o0 + j2][f0] = gv;
        }
        __syncthreads();
        // ---- out[t][f] += w3[t][oc+j] * g[j][f], 16t x 4f per thread ----
        for (int j = 0; j < 32; ++j) {
            float4 g4 = *(const float4*)&gb[j][f0];
#pragma unroll
            for (int tg = 0; tg < 4; ++tg) {
                float4 wv = *(const float4*)&w3c[j][tq * 16 + tg * 4];
                fma4(oacc[tg * 4 + 0], wv.x, g4);
                fma4(oacc[tg * 4 + 1], wv.y, g4);
                fma4(oacc[tg * 4 + 2], wv.z, g4);
                fma4(oacc[tg * 4 + 3], wv.w, g4);
            }
        }
        __syncthreads();
    }
#pragma unroll
    for (int tt = 0; tt < 16; ++tt) {
        int t = tq * 16 + tt;
        size_t gi = ((size_t)(b * Tc + t) * Nc + n) * 128 + f0;
        ushort4 xv = *(const ushort4*)&X2b[gi];
        float bt3 = b3[t];
        float4 r;
        r.x = oacc[tt].x + bt3 + bu2f(xv.x);
        r.y = oacc[tt].y + bt3 + bu2f(xv.y);
        r.z = oacc[tt].z + bt3 + bu2f(xv.z);
        r.w = oacc[tt].w + bt3 + bu2f(xv.w);
        *(float4*)&out[gi] = r;
    }
}

extern "C" void kernel_launch(void* const* d_in, const int* in_sizes, int n_in,
                              void* d_out, int out_size, void* d_ws, size_t ws_size,
                              hipStream_t stream) {
    const float* x      = (const float*)d_in[0];
    const float* norm_w = (const float*)d_in[1];
    const float* q_w    = (const float*)d_in[2];
    const float* q_b    = (const float*)d_in[3];
    const float* key_p  = (const float*)d_in[4];
    const float* v_w    = (const float*)d_in[5];
    const float* v_b    = (const float*)d_in[6];
    const float* alpha  = (const float*)d_in[7];
    const float* beta   = (const float*)d_in[8];
    const float* w1     = (const float*)d_in[9];
    const float* b1     = (const float*)d_in[10];
    const float* w2     = (const float*)d_in[11];
    const float* b2     = (const float*)d_in[12];
    const float* w3     = (const float*)d_in[13];
    const float* b3     = (const float*)d_in[14];
    float* out = (float*)d_out;

    char* ws = (char*)d_ws;
    float* inv1 = (float*)ws;                                    // 262144 f
    float* inv2 = inv1 + (size_t)Bc * NF;                        // 262144 f
    float* VLp  = inv2 + (size_t)Bc * NF;                        // 1048576 f
    float* M2p  = VLp + (size_t)Bc * Tc * Hc * Rc * Dc;          // 32768 f
    float* S2p  = M2p + (size_t)Bc * Tc * Hc * Rc;               // 32768 f
    unsigned short* Lb  = (unsigned short*)(S2p + (size_t)Bc * Tc * Hc * Rc);
    unsigned short* XVb = Lb  + (size_t)TOK * 128;
    unsigned short* X2b = XVb + (size_t)TOK * 128;               // total ~198.3 MiB

    k_rms_f32 <<<Bc * NF / 256, 256, 0, stream>>>(x, inv1);
    k_proj    <<<TOK / 64,      256, 0, stream>>>(x, inv1, norm_w, q_w, q_b, v_w, v_b, key_p, Lb, XVb);
    k_land    <<<Bc * Tc * Hc,  256, 0, stream>>>(Lb, XVb, VLp, M2p, S2p);
    k_out1    <<<TOK / 8,       256, 0, stream>>>(x, Lb, XVb, VLp, M2p, S2p, alpha, beta, X2b);
    k_rms_bf16<<<Bc * NF / 256, 256, 0, stream>>>(X2b, inv2);
    k_ffn     <<<Bc * Nc,       256, 0, stream>>>(X2b, inv2, norm_w, w1, b1, w2, b2, w3, b3, out);
}

// Round 3
// 1006.516 us; speedup vs baseline: 2.6997x; 2.6997x over previous
//
#include <hip/hip_runtime.h>

#define DEV static __device__ __forceinline__

constexpr int Bc = 2, Tc = 128, Nc = 1024, Fc = 128, Hc = 4, Rc = 32, Dc = 32;
constexpr int NF  = Nc * Fc;        // 131072 = 2^17
constexpr int TOK = Bc * Tc * Nc;   // 262144
constexpr float EPSc = 1e-6f;
constexpr float RSD  = 0.17677669529663687f;  // 1/sqrt(32)

typedef __bf16 bf16x8 __attribute__((ext_vector_type(8)));
typedef float  f32x16 __attribute__((ext_vector_type(16)));

DEV unsigned short f2bu(float f) {              // fp32 -> bf16 (RNE)
    unsigned u = __builtin_bit_cast(unsigned, f);
    u += 0x7fffu + ((u >> 16) & 1u);
    return (unsigned short)(u >> 16);
}
DEV float bu2f(unsigned short s) {
    return __builtin_bit_cast(float, ((unsigned)s) << 16);
}
DEV float sigmoidf_(float z) { return 1.f / (1.f + __expf(-z)); }
DEV void fma4(float4& a, float s, const float4& b) {
    a.x = fmaf(s, b.x, a.x); a.y = fmaf(s, b.y, a.y);
    a.z = fmaf(s, b.z, a.z); a.w = fmaf(s, b.w, a.w);
}
DEV f32x16 zero16() { f32x16 z;
#pragma unroll
    for (int i = 0; i < 16; i++) z[i] = 0.f;
    return z; }

// ---------------- K1/K5: rmsnorm-over-t scale factors -----------------
__global__ void k_rms_f32(const float* __restrict__ x, float* __restrict__ inv) {
    int j = blockIdx.x * 256 + threadIdx.x;     // j = b*NF + p
    int b = j >> 17;
    int p = j & (NF - 1);
    const float* px = x + (size_t)b * Tc * NF + p;
    float s = 0.f;
#pragma unroll 8
    for (int t = 0; t < Tc; ++t) { float v = px[(size_t)t * NF]; s = fmaf(v, v, s); }
    inv[j] = rsqrtf(s * (1.f / Tc) + EPSc);
}

__global__ void k_rms_bf16(const unsigned short* __restrict__ xb, float* __restrict__ inv) {
    int j = blockIdx.x * 256 + threadIdx.x;
    int b = j >> 17;
    int p = j & (NF - 1);
    const unsigned short* px = xb + (size_t)b * Tc * NF + p;
    float s = 0.f;
#pragma unroll 8
    for (int t = 0; t < Tc; ++t) { float v = bu2f(px[(size_t)t * NF]); s = fmaf(v, v, s); }
    inv[j] = rsqrtf(s * (1.f / Tc) + EPSc);
}

// ---------------- K2: q/v projection + attention logits ----------------
__global__ __launch_bounds__(256, 1) void k_proj(
    const float* __restrict__ x, const float* __restrict__ inv1, const float* __restrict__ nw,
    const float* __restrict__ q_w, const float* __restrict__ q_b,
    const float* __restrict__ v_w, const float* __restrict__ v_b,
    const float* __restrict__ key_p,
    unsigned short* __restrict__ Lb, unsigned short* __restrict__ XVb)
{
    __shared__ float s_xn[128][68];
    __shared__ float s_wc[128][68];
    __shared__ float s_q [64][132];
    __shared__ float s_kp[4][32][32];
    int tid = threadIdx.x;
    int tk0 = blockIdx.x * 64;

    for (int i = tid; i < 4096; i += 256) {
        int r = i >> 7; int rem = i & 127; int h = rem >> 5; int d = rem & 31;
        s_kp[h][d][r] = key_p[i] * RSD;
    }
    for (int i = tid; i < 8192; i += 256) {
        int tt = i >> 7; int c = i & 127;
        int tk = tk0 + tt;
        int b = tk >> 17; int n = tk & (Nc - 1);
        s_xn[c][tt] = x[(size_t)tk * 128 + c] * inv1[(size_t)b * NF + n * 128 + c] * nw[c];
    }
    __syncthreads();

    int ttk = tid & 15, to = tid >> 4;
    for (int chunk = 0; chunk < 4; ++chunk) {
        const float* W  = (chunk < 2) ? q_w : v_w;
        const float* Bv = (chunk < 2) ? q_b : v_b;
        int wbase = (chunk & 1) * 64;
        for (int i = tid; i < 8192; i += 256) {
            int j = i >> 7; int c = i & 127;
            s_wc[c][j] = W[(size_t)(wbase + j) * 128 + c];
        }
        __syncthreads();
        float acc[4][4];
#pragma unroll
        for (int j2 = 0; j2 < 4; j2++) {
            float bb = Bv[wbase + to * 4 + j2];
            acc[0][j2] = bb; acc[1][j2] = bb; acc[2][j2] = bb; acc[3][j2] = bb;
        }
        for (int c = 0; c < 128; ++c) {
            float4 xa = *(const float4*)&s_xn[c][ttk * 4];
            float4 wa = *(const float4*)&s_wc[c][to * 4];
            float xs[4] = {xa.x, xa.y, xa.z, xa.w};
            float wv[4] = {wa.x, wa.y, wa.z, wa.w};
#pragma unroll
            for (int i2 = 0; i2 < 4; i2++)
#pragma unroll
                for (int j2 = 0; j2 < 4; j2++)
                    acc[i2][j2] = fmaf(xs[i2], wv[j2], acc[i2][j2]);
        }
        int olocal = wbase + to * 4;
        if (chunk < 2) {
#pragma unroll
            for (int i2 = 0; i2 < 4; i2++) {
                int tok = ttk * 4 + i2;
#pragma unroll
                for (int j2 = 0; j2 < 4; j2++) s_q[tok][olocal + j2] = acc[i2][j2];
            }
        } else {
#pragma unroll
            for (int i2 = 0; i2 < 4; i2++) {
                int tk = tk0 + ttk * 4 + i2;
                ushort4 pk;
                pk.x = f2bu(acc[i2][0]); pk.y = f2bu(acc[i2][1]);
                pk.z = f2bu(acc[i2][2]); pk.w = f2bu(acc[i2][3]);
                *(ushort4*)&XVb[(size_t)tk * 128 + olocal] = pk;
            }
        }
        __syncthreads();
    }

#pragma unroll
    for (int pass = 0; pass < 2; ++pass) {
        int hr0 = pass * 64 + (tid >> 4) * 4;
        int h = hr0 >> 5, r0 = hr0 & 31;
        int tq = tid & 15;
        float a[4][4];
#pragma unroll
        for (int i2 = 0; i2 < 4; i2++) { a[i2][0] = 0; a[i2][1] = 0; a[i2][2] = 0; a[i2][3] = 0; }
        for (int d = 0; d < 32; ++d) {
            float4 kv = *(const float4*)&s_kp[h][d][r0];
            float kk[4] = {kv.x, kv.y, kv.z, kv.w};
#pragma unroll
            for (int i2 = 0; i2 < 4; i2++) {
                float qv = s_q[tq * 4 + i2][h * 32 + d];
#pragma unroll
                for (int j2 = 0; j2 < 4; j2++) a[i2][j2] = fmaf(qv, kk[j2], a[i2][j2]);
            }
        }
#pragma unroll
        for (int i2 = 0; i2 < 4; i2++) {
            int tk = tk0 + tq * 4 + i2;
            ushort4 pk;
            pk.x = f2bu(a[i2][0]); pk.y = f2bu(a[i2][1]);
            pk.z = f2bu(a[i2][2]); pk.w = f2bu(a[i2][3]);
            *(ushort4*)&Lb[(size_t)tk * 128 + h * 32 + r0] = pk;
        }
    }
}

// ---------------- K3: landmark aggregation + n-softmax stats ----------------
__global__ void k_land(const unsigned short* __restrict__ Lb, const unsigned short* __restrict__ XVb,
                       float* __restrict__ VL, float* __restrict__ M2, float* __restrict__ S2)
{
    __shared__ float sL [64][33];
    __shared__ float sXV[64][36];
    int tid = threadIdx.x;
    int blk = blockIdx.x;               // bt*4 + h
    int h = blk & 3; int bt = blk >> 2;
    size_t base = (size_t)bt * Nc * 128 + h * 32;
    int r_acc = tid >> 3, d0 = (tid & 7) * 4;
    float a0 = 0, a1 = 0, a2 = 0, a3 = 0;
    float m_run = -1e30f, s_run = 0.f;
    for (int n0 = 0; n0 < Nc; n0 += 64) {
        for (int k = tid; k < 2048; k += 256) {
            int i = k >> 5, rr = k & 31;
            size_t g = base + (size_t)(n0 + i) * 128 + rr;
            sL [i][rr] = bu2f(Lb [g]);
            sXV[i][rr] = bu2f(XVb[g]);
        }
        __syncthreads();
        if (tid < 32) {
            float m = m_run, s = s_run;
#pragma unroll 4
            for (int i = 0; i < 64; i++) {
                float v = sL[i][tid];
                float mn = fmaxf(m, v);
                s = s * __expf(m - mn) + __expf(v - mn);
                m = mn;
            }
            m_run = m; s_run = s;
        }
        __syncthreads();
        if (tid < 64) {
            float mx = -1e30f;
#pragma unroll 4
            for (int rr = 0; rr < 32; rr++) mx = fmaxf(mx, sL[tid][rr]);
            float sm = 0.f;
#pragma unroll 4
            for (int rr = 0; rr < 32; rr++) { float e = __expf(sL[tid][rr] - mx); sL[tid][rr] = e; sm += e; }
            float iv = 1.f / sm;
#pragma unroll 4
            for (int rr = 0; rr < 32; rr++) sL[tid][rr] *= iv;
        }
        __syncthreads();
#pragma unroll 2
        for (int i = 0; i < 64; i++) {
            float p = sL[i][r_acc];
            float4 v = *(const float4*)&sXV[i][d0];
            a0 = fmaf(p, v.x, a0); a1 = fmaf(p, v.y, a1);
            a2 = fmaf(p, v.z, a2); a3 = fmaf(p, v.w, a3);
        }
        __syncthreads();
    }
    *(float4*)&VL[((size_t)blk * 32 + r_acc) * 32 + d0] = make_float4(a0, a1, a2, a3);
    if (tid < 32) { M2[blk * 32 + tid] = m_run; S2[blk * 32 + tid] = s_run; }
}

// ---------------- K4: scatter landmarks + gates + first residual ----------------
__global__ void k_out1(const float* __restrict__ x,
                       const unsigned short* __restrict__ Lb, const unsigned short* __restrict__ XVb,
                       const float* __restrict__ VL, const float* __restrict__ M2, const float* __restrict__ S2,
                       const float* __restrict__ alpha, const float* __restrict__ beta,
                       unsigned short* __restrict__ X2b)
{
    __shared__ float sVL[128][32];
    __shared__ float sP[8][128];
    __shared__ float sM[128], sSi[128], sAB[8];
    int tid = threadIdx.x;
    int tk0 = blockIdx.x * 8;
    int bt = tk0 >> 10;
    for (int k = tid; k < 4096; k += 256) sVL[k >> 5][k & 31] = VL[(size_t)bt * 4096 + k];
    if (tid < 128) { sM[tid] = M2[bt * 128 + tid]; sSi[tid] = 1.f / S2[bt * 128 + tid]; }
    if (tid < 8)   sAB[tid] = (tid < 4) ? sigmoidf_(alpha[tid]) : sigmoidf_(beta[tid - 4]);
    __syncthreads();
    for (int k = tid; k < 1024; k += 256) {
        int ti = k >> 7, f = k & 127;
        float lv = bu2f(Lb[(size_t)(tk0 + ti) * 128 + f]);
        sP[ti][f] = __expf(lv - sM[f]) * sSi[f];
    }
    __syncthreads();
    int ti = tid >> 5, quad = tid & 31;
    int h = quad >> 3, d0 = (quad & 7) * 4;
    float a0 = 0, a1 = 0, a2 = 0, a3 = 0;
    int hr0 = h * 32;
#pragma unroll 4
    for (int r = 0; r < 32; ++r) {
        float p = sP[ti][hr0 + r];
        float4 v = *(const float4*)&sVL[hr0 + r][d0];
        a0 = fmaf(p, v.x, a0); a1 = fmaf(p, v.y, a1);
        a2 = fmaf(p, v.z, a2); a3 = fmaf(p, v.w, a3);
    }
    size_t gi = (size_t)(tk0 + ti) * 128 + quad * 4;
    ushort4 xv4 = *(const ushort4*)&XVb[gi];
    float sa = sAB[h], sb = sAB[4 + h];
    float o0 = fmaf(sb, a0, fmaf(sa, bu2f(xv4.x), x[gi + 0]));
    float o1 = fmaf(sb, a1, fmaf(sa, bu2f(xv4.y), x[gi + 1]));
    float o2 = fmaf(sb, a2, fmaf(sa, bu2f(xv4.z), x[gi + 2]));
    float o3 = fmaf(sb, a3, fmaf(sa, bu2f(xv4.w), x[gi + 3]));
    ushort4 pk; pk.x = f2bu(o0); pk.y = f2bu(o1); pk.z = f2bu(o2); pk.w = f2bu(o3);
    *(ushort4*)&X2b[gi] = pk;
}

// ---------------- weight fp32 -> bf16 conversion ----------------
__global__ void k_cvt(const float* __restrict__ w, unsigned short* __restrict__ o, int n) {
    int i = blockIdx.x * 256 + threadIdx.x;
    if (i < n) o[i] = f2bu(w[i]);
}

// ---------------- K6: MFMA FFN over the t axis + final residual ----------------
// block = (b,n), 4 waves. GEMM1/2: H=W1/2(512x128t)*XN(128t x 128f); G=silu(H1)*H2;
// GEMM3: OUT(128t x 128f) = W3(128x512)*G. o-chunks of 64, gT in LDS only.
// mfma_f32_32x32x16_bf16: A[row=l&31][k=8*(l>>5)+j], B[k=8*(l>>5)+j][col=l&31],
// D: col=l&31, row=(r&3)+8*(r>>2)+4*(l>>5).
__global__ __launch_bounds__(256, 2) void k_ffn_mfma(
    const unsigned short* __restrict__ X2b, const float* __restrict__ inv2, const float* __restrict__ nw,
    const unsigned short* __restrict__ w1b, const float* __restrict__ b1,
    const unsigned short* __restrict__ w2b, const float* __restrict__ b2,
    const unsigned short* __restrict__ w3b, const float* __restrict__ b3,
    float* __restrict__ out)
{
    __shared__ unsigned short gT[128 * 72] __attribute__((aligned(16)));  // [f][o64+pad], 144B stride

    const int tid  = threadIdx.x;
    const int lane = tid & 63;
    const int wv   = tid >> 6;
    const int lr   = lane & 31;
    const int lhi  = lane >> 5;
    const int blk  = blockIdx.x;
    const int b    = blk >> 10, n = blk & 1023;

    const int mrow = (wv & 1) * 32;     // o-local base (phase B)
    const int fh   = (wv >> 1) * 64;    // f base, 2 tiles (phase B)
    const int t0   = wv * 32;           // t-tile base (phase C)

    // ---- preload XN B-fragments into registers (2 f-tiles x 8 k-steps) ----
    bf16x8 xnf[2][8];
#pragma unroll
    for (int ft = 0; ft < 2; ++ft) {
        const int f = fh + ft * 32 + lr;
        const float scale = inv2[(size_t)blk * 128 + f] * nw[f];
        const unsigned short* px = X2b + ((size_t)(b * Tc) * Nc + n) * 128 + f;
#pragma unroll
        for (int s = 0; s < 8; ++s) {
            bf16x8 v;
#pragma unroll
            for (int j = 0; j < 8; ++j) {
                int t = s * 16 + lhi * 8 + j;
                float xv = bu2f(px[(size_t)t * NF]) * scale;
                v[j] = (__bf16)xv;
            }
            xnf[ft][s] = v;
        }
    }

    f32x16 oacc[4];
#pragma unroll
    for (int c = 0; c < 4; ++c) oacc[c] = zero16();

    const unsigned short* w1r = w1b + (size_t)(mrow + lr) * 128 + lhi * 8;
    const unsigned short* w2r = w2b + (size_t)(mrow + lr) * 128 + lhi * 8;
    const unsigned short* w3r = w3b + (size_t)(t0 + lr) * 512 + lhi * 8;

    for (int oc = 0; oc < 512; oc += 64) {
        // ---------- phase B: H1/H2 for this o-chunk ----------
        f32x16 h1a = zero16(), h1b = zero16(), h2a = zero16(), h2b = zero16();
        const unsigned short* pw1 = w1r + (size_t)oc * 128;
        const unsigned short* pw2 = w2r + (size_t)oc * 128;
#pragma unroll
        for (int s = 0; s < 8; ++s) {
            bf16x8 a1 = *(const bf16x8*)(pw1 + s * 16);
            bf16x8 a2 = *(const bf16x8*)(pw2 + s * 16);
            h1a = __builtin_amdgcn_mfma_f32_32x32x16_bf16(a1, xnf[0][s], h1a, 0, 0, 0);
            h1b = __builtin_amdgcn_mfma_f32_32x32x16_bf16(a1, xnf[1][s], h1b, 0, 0, 0);
            h2a = __builtin_amdgcn_mfma_f32_32x32x16_bf16(a2, xnf[0][s], h2a, 0, 0, 0);
            h2b = __builtin_amdgcn_mfma_f32_32x32x16_bf16(a2, xnf[1][s], h2b, 0, 0, 0);
        }
        // g = silu(h1 + b1) * (h2 + b2), pack 4 o-rows -> b64 LDS write
#pragma unroll
        for (int ft = 0; ft < 2; ++ft) {
            const int fcol = fh + ft * 32 + lr;
#pragma unroll
            for (int q = 0; q < 4; ++q) {
                ushort4 pk;
#pragma unroll
                for (int e = 0; e < 4; ++e) {
                    const int r = q * 4 + e;
                    const int orow = oc + mrow + e + 8 * q + 4 * lhi;
                    float z  = (ft ? h1b[r] : h1a[r]) + b1[orow];
                    float h2v = (ft ? h2b[r] : h2a[r]) + b2[orow];
                    float g  = z * sigmoidf_(z) * h2v;
                    unsigned short gb = __builtin_bit_cast(unsigned short, (__bf16)g);
                    if (e == 0) pk.x = gb; else if (e == 1) pk.y = gb;
                    else if (e == 2) pk.z = gb; else pk.w = gb;
                }
                const int o_l = mrow + 8 * q + 4 * lhi;
                *(ushort4*)&gT[fcol * 72 + o_l] = pk;
            }
        }
        __syncthreads();
        // ---------- phase C: OUT += W3[:, oc..oc+63] * G ----------
        const unsigned short* pw3 = w3r + oc;
#pragma unroll
        for (int s = 0; s < 4; ++s) {
            bf16x8 a3 = *(const bf16x8*)(pw3 + s * 16);
#pragma unroll
            for (int c = 0; c < 4; ++c) {
                bf16x8 bg = *(const bf16x8*)&gT[(c * 32 + lr) * 72 + s * 16 + lhi * 8];
                oacc[c] = __builtin_amdgcn_mfma_f32_32x32x16_bf16(a3, bg, oacc[c], 0, 0, 0);
            }
        }
        __syncthreads();
    }

    // ---------- epilogue: out = acc + b3[t] + X2 ----------
#pragma unroll
    for (int r = 0; r < 16; ++r) {
        const int t = t0 + (r & 3) + 8 * (r >> 2) + 4 * lhi;
        const float bt3 = b3[t];
        const size_t rowbase = ((size_t)(b * Tc + t) * Nc + n) * 128;
#pragma unroll
        for (int c = 0; c < 4; ++c) {
            const int f = c * 32 + lr;
            const size_t gi = rowbase + f;
            out[gi] = oacc[c][r] + bt3 + bu2f(X2b[gi]);
        }
    }
}

extern "C" void kernel_launch(void* const* d_in, const int* in_sizes, int n_in,
                              void* d_out, int out_size, void* d_ws, size_t ws_size,
                              hipStream_t stream) {
    const float* x      = (const float*)d_in[0];
    const float* norm_w = (const float*)d_in[1];
    const float* q_w    = (const float*)d_in[2];
    const float* q_b    = (const float*)d_in[3];
    const float* key_p  = (const float*)d_in[4];
    const float* v_w    = (const float*)d_in[5];
    const float* v_b    = (const float*)d_in[6];
    const float* alpha  = (const float*)d_in[7];
    const float* beta   = (const float*)d_in[8];
    const float* w1     = (const float*)d_in[9];
    const float* b1     = (const float*)d_in[10];
    const float* w2     = (const float*)d_in[11];
    const float* b2     = (const float*)d_in[12];
    const float* w3     = (const float*)d_in[13];
    const float* b3     = (const float*)d_in[14];
    float* out = (float*)d_out;

    char* ws = (char*)d_ws;
    float* inv1 = (float*)ws;                                    // 262144 f
    float* inv2 = inv1 + (size_t)Bc * NF;                        // 262144 f
    float* VLp  = inv2 + (size_t)Bc * NF;                        // 1048576 f
    float* M2p  = VLp + (size_t)Bc * Tc * Hc * Rc * Dc;          // 32768 f
    float* S2p  = M2p + (size_t)Bc * Tc * Hc * Rc;               // 32768 f
    unsigned short* Lb  = (unsigned short*)(S2p + (size_t)Bc * Tc * Hc * Rc);
    unsigned short* XVb = Lb  + (size_t)TOK * 128;
    unsigned short* X2b = XVb + (size_t)TOK * 128;               // total ~198.3 MiB

    // bf16 weight copies aliased onto Lb (dead after k_out1)
    unsigned short* w1bf = Lb;
    unsigned short* w2bf = Lb + 65536;
    unsigned short* w3bf = Lb + 131072;

    k_rms_f32 <<<Bc * NF / 256, 256, 0, stream>>>(x, inv1);
    k_proj    <<<TOK / 64,      256, 0, stream>>>(x, inv1, norm_w, q_w, q_b, v_w, v_b, key_p, Lb, XVb);
    k_land    <<<Bc * Tc * Hc,  256, 0, stream>>>(Lb, XVb, VLp, M2p, S2p);
    k_out1    <<<TOK / 8,       256, 0, stream>>>(x, Lb, XVb, VLp, M2p, S2p, alpha, beta, X2b);
    k_cvt     <<<256, 256, 0, stream>>>(w1, w1bf, 65536);
    k_cvt     <<<256, 256, 0, stream>>>(w2, w2bf, 65536);
    k_cvt     <<<256, 256, 0, stream>>>(w3, w3bf, 65536);
    k_rms_bf16<<<Bc * NF / 256, 256, 0, stream>>>(X2b, inv2);
    k_ffn_mfma<<<Bc * Nc,       256, 0, stream>>>(X2b, inv2, norm_w, w1bf, b1, w2bf, b2, w3bf, b3, out);
}

// Round 5
// 692.230 us; speedup vs baseline: 3.9254x; 1.4540x over previous
//
#include <hip/hip_runtime.h>

#define DEV static __device__ __forceinline__

constexpr int Bc = 2, Tc = 128, Nc = 1024, Fc = 128, Hc = 4, Rc = 32, Dc = 32;
constexpr int NF  = Nc * Fc;        // 131072 = 2^17
constexpr int TOK = Bc * Tc * Nc;   // 262144
constexpr float EPSc = 1e-6f;
constexpr float RSD  = 0.17677669529663687f;  // 1/sqrt(32)

typedef __bf16 bf16x8 __attribute__((ext_vector_type(8)));
typedef float  f32x16 __attribute__((ext_vector_type(16)));

DEV unsigned short f2bu(float f) {              // fp32 -> bf16 (RNE)
    unsigned u = __builtin_bit_cast(unsigned, f);
    u += 0x7fffu + ((u >> 16) & 1u);
    return (unsigned short)(u >> 16);
}
DEV float bu2f(unsigned short s) {
    return __builtin_bit_cast(float, ((unsigned)s) << 16);
}
DEV float sigmoidf_(float z) { return 1.f / (1.f + __expf(-z)); }
DEV f32x16 zero16() { f32x16 z;
#pragma unroll
    for (int i = 0; i < 16; i++) z[i] = 0.f;
    return z; }

// ---------------- K1/K5: rmsnorm-over-t scale factors -----------------
__global__ void k_rms_f32(const float* __restrict__ x, float* __restrict__ inv) {
    int j = blockIdx.x * 256 + threadIdx.x;     // j = b*NF + p
    int b = j >> 17;
    int p = j & (NF - 1);
    const float* px = x + (size_t)b * Tc * NF + p;
    float s = 0.f;
#pragma unroll 8
    for (int t = 0; t < Tc; ++t) { float v = px[(size_t)t * NF]; s = fmaf(v, v, s); }
    inv[j] = rsqrtf(s * (1.f / Tc) + EPSc);
}

__global__ void k_rms_bf16(const unsigned short* __restrict__ xb, float* __restrict__ inv) {
    int j = blockIdx.x * 256 + threadIdx.x;
    int b = j >> 17;
    int p = j & (NF - 1);
    const unsigned short* px = xb + (size_t)b * Tc * NF + p;
    float s = 0.f;
#pragma unroll 8
    for (int t = 0; t < Tc; ++t) { float v = bu2f(px[(size_t)t * NF]); s = fmaf(v, v, s); }
    inv[j] = rsqrtf(s * (1.f / Tc) + EPSc);
}

// ---------------- weight fp32 -> bf16 conversion ----------------
__global__ void k_cvt(const float* __restrict__ w, unsigned short* __restrict__ o, int n) {
    int i = blockIdx.x * 256 + threadIdx.x;
    if (i < n) o[i] = f2bu(w[i]);
}

// ---------------- K_qk: fold q_w and key_p into QK (128x128), + biases ----------------
// Wcat rows 0..127: Wcat[h*32+r][c] = RSD * sum_d q_w[h*32+d][c] * key_p[r][h][d]
// bias[h*32+r] = RSD * sum_d q_b[h*32+d] * key_p[r][h][d];  bias[128+o] = v_b[o]
__global__ void k_qk(const float* __restrict__ q_w, const float* __restrict__ q_b,
                     const float* __restrict__ key_p, const float* __restrict__ v_b,
                     unsigned short* __restrict__ Wcat, float* __restrict__ bias)
{
    __shared__ float sqw[32][128];   // [d][c] for this h
    __shared__ float skp[32][32];    // [r][d], pre-scaled by RSD
    int h = blockIdx.x, tid = threadIdx.x;
    for (int i = tid; i < 4096; i += 256) {
        int d = i >> 7, c = i & 127;
        sqw[d][c] = q_w[(size_t)(h * 32 + d) * 128 + c];
    }
    for (int i = tid; i < 1024; i += 256) {
        int r = i >> 5, d = i & 31;
        skp[r][d] = key_p[(size_t)(r * 4 + h) * 32 + d] * RSD;
    }
    __syncthreads();
    int r = tid >> 3;
    int c0 = (tid & 7) * 16;
    for (int cc = 0; cc < 16; ++cc) {
        int c = c0 + cc;
        float s = 0.f;
#pragma unroll
        for (int d = 0; d < 32; ++d) s = fmaf(sqw[d][c], skp[r][d], s);
        Wcat[(size_t)(h * 32 + r) * 128 + c] = f2bu(s);
    }
    if (tid < 32) {
        float s = 0.f;
#pragma unroll
        for (int d = 0; d < 32; ++d) s = fmaf(q_b[h * 32 + d], skp[tid][d], s);
        bias[h * 32 + tid] = s;
    }
    if (h == 0 && tid >= 64 && tid < 192) bias[128 + tid - 64] = v_b[tid - 64];
}

// ---------------- K2: MFMA projection: [L ; XV] = XN @ Wcat^T + bias ----------------
// grid TOK/128, 4 waves; wave = 32 tokens x 256 outputs (8 o-tiles of 32).
// No LDS. A (tokens) held in regs; rmsnorm fused into A load.
__global__ __launch_bounds__(256, 4) void k_projm(
    const float* __restrict__ x, const float* __restrict__ inv1, const float* __restrict__ nw,
    const unsigned short* __restrict__ Wcat, const float* __restrict__ bias,
    unsigned short* __restrict__ Lb, unsigned short* __restrict__ XVb)
{
    const int tid = threadIdx.x, lane = tid & 63, wv = tid >> 6;
    const int lr = lane & 31, lhi = lane >> 5;
    const int tokb = blockIdx.x * 128 + wv * 32;
    const int tok = tokb + lr;
    const int b = tok >> 17, n = tok & 1023;
    const float* px = x + (size_t)tok * 128;
    const float* pi = inv1 + (size_t)b * NF + n * 128;

    bf16x8 af[8];
#pragma unroll
    for (int s = 0; s < 8; ++s) {
        const int c0 = s * 16 + lhi * 8;
        float4 xa = *(const float4*)(px + c0);
        float4 xb = *(const float4*)(px + c0 + 4);
        float4 ia = *(const float4*)(pi + c0);
        float4 ib = *(const float4*)(pi + c0 + 4);
        float4 na = *(const float4*)(nw + c0);
        float4 nb = *(const float4*)(nw + c0 + 4);
        bf16x8 v;
        v[0] = (__bf16)(xa.x * ia.x * na.x);
        v[1] = (__bf16)(xa.y * ia.y * na.y);
        v[2] = (__bf16)(xa.z * ia.z * na.z);
        v[3] = (__bf16)(xa.w * ia.w * na.w);
        v[4] = (__bf16)(xb.x * ib.x * nb.x);
        v[5] = (__bf16)(xb.y * ib.y * nb.y);
        v[6] = (__bf16)(xb.z * ib.z * nb.z);
        v[7] = (__bf16)(xb.w * ib.w * nb.w);
        af[s] = v;
    }

#pragma unroll
    for (int ot = 0; ot < 8; ++ot) {
        const unsigned short* pw = Wcat + (size_t)(ot * 32 + lr) * 128 + lhi * 8;
        f32x16 acc = zero16();
#pragma unroll
        for (int s = 0; s < 8; ++s) {
            bf16x8 bw = *(const bf16x8*)(pw + s * 16);
            acc = __builtin_amdgcn_mfma_f32_32x32x16_bf16(af[s], bw, acc, 0, 0, 0);
        }
        const int o = ot * 32 + lr;
        const float bv = bias[o];
        unsigned short* dst = (ot < 4) ? Lb : XVb;
        const int oo = (ot < 4) ? o : o - 128;
#pragma unroll
        for (int r = 0; r < 16; ++r) {
            const int trow = tokb + (r & 3) + 8 * (r >> 2) + 4 * lhi;
            dst[(size_t)trow * 128 + oo] = f2bu(acc[r] + bv);
        }
    }
}

// ---------------- K3: landmark aggregation + n-softmax stats ----------------
__global__ void k_land(const unsigned short* __restrict__ Lb, const unsigned short* __restrict__ XVb,
                       float* __restrict__ VL, float* __restrict__ M2, float* __restrict__ S2)
{
    __shared__ float sL [64][33];
    __shared__ float sXV[64][36];
    int tid = threadIdx.x;
    int blk = blockIdx.x;               // bt*4 + h
    int h = blk & 3; int bt = blk >> 2;
    size_t base = (size_t)bt * Nc * 128 + h * 32;
    int r_acc = tid >> 3, d0 = (tid & 7) * 4;
    float a0 = 0, a1 = 0, a2 = 0, a3 = 0;
    float m_run = -1e30f, s_run = 0.f;
    for (int n0 = 0; n0 < Nc; n0 += 64) {
        for (int k = tid; k < 2048; k += 256) {
            int i = k >> 5, rr = k & 31;
            size_t g = base + (size_t)(n0 + i) * 128 + rr;
            sL [i][rr] = bu2f(Lb [g]);
            sXV[i][rr] = bu2f(XVb[g]);
        }
        __syncthreads();
        if (tid < 32) {
            float m = m_run, s = s_run;
#pragma unroll 4
            for (int i = 0; i < 64; i++) {
                float v = sL[i][tid];
                float mn = fmaxf(m, v);
                s = s * __expf(m - mn) + __expf(v - mn);
                m = mn;
            }
            m_run = m; s_run = s;
        }
        __syncthreads();
        if (tid < 64) {
            float mx = -1e30f;
#pragma unroll 4
            for (int rr = 0; rr < 32; rr++) mx = fmaxf(mx, sL[tid][rr]);
            float sm = 0.f;
#pragma unroll 4
            for (int rr = 0; rr < 32; rr++) { float e = __expf(sL[tid][rr] - mx); sL[tid][rr] = e; sm += e; }
            float iv = 1.f / sm;
#pragma unroll 4
            for (int rr = 0; rr < 32; rr++) sL[tid][rr] *= iv;
        }
        __syncthreads();
#pragma unroll 2
        for (int i = 0; i < 64; i++) {
            float p = sL[i][r_acc];
            float4 v = *(const float4*)&sXV[i][d0];
            a0 = fmaf(p, v.x, a0); a1 = fmaf(p, v.y, a1);
            a2 = fmaf(p, v.z, a2); a3 = fmaf(p, v.w, a3);
        }
        __syncthreads();
    }
    *(float4*)&VL[((size_t)blk * 32 + r_acc) * 32 + d0] = make_float4(a0, a1, a2, a3);
    if (tid < 32) { M2[blk * 32 + tid] = m_run; S2[blk * 32 + tid] = s_run; }
}

// ---------------- K4: scatter landmarks + gates + first residual ----------------
__global__ void k_out1(const float* __restrict__ x,
                       const unsigned short* __restrict__ Lb, const unsigned short* __restrict__ XVb,
                       const float* __restrict__ VL, const float* __restrict__ M2, const float* __restrict__ S2,
                       const float* __restrict__ alpha, const float* __restrict__ beta,
                       unsigned short* __restrict__ X2b)
{
    __shared__ float sVL[128][32];
    __shared__ float sP[8][128];
    __shared__ float sM[128], sSi[128], sAB[8];
    int tid = threadIdx.x;
    int tk0 = blockIdx.x * 8;
    int bt = tk0 >> 10;
    for (int k = tid; k < 4096; k += 256) sVL[k >> 5][k & 31] = VL[(size_t)bt * 4096 + k];
    if (tid < 128) { sM[tid] = M2[bt * 128 + tid]; sSi[tid] = 1.f / S2[bt * 128 + tid]; }
    if (tid < 8)   sAB[tid] = (tid < 4) ? sigmoidf_(alpha[tid]) : sigmoidf_(beta[tid - 4]);
    __syncthreads();
    for (int k = tid; k < 1024; k += 256) {
        int ti = k >> 7, f = k & 127;
        float lv = bu2f(Lb[(size_t)(tk0 + ti) * 128 + f]);
        sP[ti][f] = __expf(lv - sM[f]) * sSi[f];
    }
    __syncthreads();
    int ti = tid >> 5, quad = tid & 31;
    int h = quad >> 3, d0 = (quad & 7) * 4;
    float a0 = 0, a1 = 0, a2 = 0, a3 = 0;
    int hr0 = h * 32;
#pragma unroll 4
    for (int r = 0; r < 32; ++r) {
        float p = sP[ti][hr0 + r];
        float4 v = *(const float4*)&sVL[hr0 + r][d0];
        a0 = fmaf(p, v.x, a0); a1 = fmaf(p, v.y, a1);
        a2 = fmaf(p, v.z, a2); a3 = fmaf(p, v.w, a3);
    }
    size_t gi = (size_t)(tk0 + ti) * 128 + quad * 4;
    ushort4 xv4 = *(const ushort4*)&XVb[gi];
    float sa = sAB[h], sb = sAB[4 + h];
    float o0 = fmaf(sb, a0, fmaf(sa, bu2f(xv4.x), x[gi + 0]));
    float o1 = fmaf(sb, a1, fmaf(sa, bu2f(xv4.y), x[gi + 1]));
    float o2 = fmaf(sb, a2, fmaf(sa, bu2f(xv4.z), x[gi + 2]));
    float o3 = fmaf(sb, a3, fmaf(sa, bu2f(xv4.w), x[gi + 3]));
    ushort4 pk; pk.x = f2bu(o0); pk.y = f2bu(o1); pk.z = f2bu(o2); pk.w = f2bu(o3);
    *(ushort4*)&X2b[gi] = pk;
}

// ---------------- K6: MFMA FFN over the t axis + final residual ----------------
__global__ __launch_bounds__(256, 2) void k_ffn_mfma(
    const unsigned short* __restrict__ X2b, const float* __restrict__ inv2, const float* __restrict__ nw,
    const unsigned short* __restrict__ w1b, const float* __restrict__ b1,
    const unsigned short* __restrict__ w2b, const float* __restrict__ b2,
    const unsigned short* __restrict__ w3b, const float* __restrict__ b3,
    float* __restrict__ out)
{
    __shared__ unsigned short gT[128 * 72] __attribute__((aligned(16)));  // [f][o64+pad], 144B stride

    const int tid  = threadIdx.x;
    const int lane = tid & 63;
    const int wv   = tid >> 6;
    const int lr   = lane & 31;
    const int lhi  = lane >> 5;
    const int blk  = blockIdx.x;
    const int b    = blk >> 10, n = blk & 1023;

    const int mrow = (wv & 1) * 32;     // o-local base (phase B)
    const int fh   = (wv >> 1) * 64;    // f base, 2 tiles (phase B)
    const int t0   = wv * 32;           // t-tile base (phase C)

    bf16x8 xnf[2][8];
#pragma unroll
    for (int ft = 0; ft < 2; ++ft) {
        const int f = fh + ft * 32 + lr;
        const float scale = inv2[(size_t)blk * 128 + f] * nw[f];
        const unsigned short* px = X2b + ((size_t)(b * Tc) * Nc + n) * 128 + f;
#pragma unroll
        for (int s = 0; s < 8; ++s) {
            bf16x8 v;
#pragma unroll
            for (int j = 0; j < 8; ++j) {
                int t = s * 16 + lhi * 8 + j;
                float xv = bu2f(px[(size_t)t * NF]) * scale;
                v[j] = (__bf16)xv;
            }
            xnf[ft][s] = v;
        }
    }

    f32x16 oacc[4];
#pragma unroll
    for (int c = 0; c < 4; ++c) oacc[c] = zero16();

    const unsigned short* w1r = w1b + (size_t)(mrow + lr) * 128 + lhi * 8;
    const unsigned short* w2r = w2b + (size_t)(mrow + lr) * 128 + lhi * 8;
    const unsigned short* w3r = w3b + (size_t)(t0 + lr) * 512 + lhi * 8;

    for (int oc = 0; oc < 512; oc += 64) {
        f32x16 h1a = zero16(), h1b = zero16(), h2a = zero16(), h2b = zero16();
        const unsigned short* pw1 = w1r + (size_t)oc * 128;
        const unsigned short* pw2 = w2r + (size_t)oc * 128;
#pragma unroll
        for (int s = 0; s < 8; ++s) {
            bf16x8 a1 = *(const bf16x8*)(pw1 + s * 16);
            bf16x8 a2 = *(const bf16x8*)(pw2 + s * 16);
            h1a = __builtin_amdgcn_mfma_f32_32x32x16_bf16(a1, xnf[0][s], h1a, 0, 0, 0);
            h1b = __builtin_amdgcn_mfma_f32_32x32x16_bf16(a1, xnf[1][s], h1b, 0, 0, 0);
            h2a = __builtin_amdgcn_mfma_f32_32x32x16_bf16(a2, xnf[0][s], h2a, 0, 0, 0);
            h2b = __builtin_amdgcn_mfma_f32_32x32x16_bf16(a2, xnf[1][s], h2b, 0, 0, 0);
        }
#pragma unroll
        for (int ft = 0; ft < 2; ++ft) {
            const int fcol = fh + ft * 32 + lr;
#pragma unroll
            for (int q = 0; q < 4; ++q) {
                ushort4 pk;
#pragma unroll
                for (int e = 0; e < 4; ++e) {
                    const int r = q * 4 + e;
                    const int orow = oc + mrow + e + 8 * q + 4 * lhi;
                    float z  = (ft ? h1b[r] : h1a[r]) + b1[orow];
                    float h2v = (ft ? h2b[r] : h2a[r]) + b2[orow];
                    float g  = z * sigmoidf_(z) * h2v;
                    unsigned short gb = __builtin_bit_cast(unsigned short, (__bf16)g);
                    if (e == 0) pk.x = gb; else if (e == 1) pk.y = gb;
                    else if (e == 2) pk.z = gb; else pk.w = gb;
                }
                const int o_l = mrow + 8 * q + 4 * lhi;
                *(ushort4*)&gT[fcol * 72 + o_l] = pk;
            }
        }
        __syncthreads();
        const unsigned short* pw3 = w3r + oc;
#pragma unroll
        for (int s = 0; s < 4; ++s) {
            bf16x8 a3 = *(const bf16x8*)(pw3 + s * 16);
#pragma unroll
            for (int c = 0; c < 4; ++c) {
                bf16x8 bg = *(const bf16x8*)&gT[(c * 32 + lr) * 72 + s * 16 + lhi * 8];
                oacc[c] = __builtin_amdgcn_mfma_f32_32x32x16_bf16(a3, bg, oacc[c], 0, 0, 0);
            }
        }
        __syncthreads();
    }

#pragma unroll
    for (int r = 0; r < 16; ++r) {
        const int t = t0 + (r & 3) + 8 * (r >> 2) + 4 * lhi;
        const float bt3 = b3[t];
        const size_t rowbase = ((size_t)(b * Tc + t) * Nc + n) * 128;
#pragma unroll
        for (int c = 0; c < 4; ++c) {
            const int f = c * 32 + lr;
            const size_t gi = rowbase + f;
            out[gi] = oacc[c][r] + bt3 + bu2f(X2b[gi]);
        }
    }
}

extern "C" void kernel_launch(void* const* d_in, const int* in_sizes, int n_in,
                              void* d_out, int out_size, void* d_ws, size_t ws_size,
                              hipStream_t stream) {
    const float* x      = (const float*)d_in[0];
    const float* norm_w = (const float*)d_in[1];
    const float* q_w    = (const float*)d_in[2];
    const float* q_b    = (const float*)d_in[3];
    const float* key_p  = (const float*)d_in[4];
    const float* v_w    = (const float*)d_in[5];
    const float* v_b    = (const float*)d_in[6];
    const float* alpha  = (const float*)d_in[7];
    const float* beta   = (const float*)d_in[8];
    const float* w1     = (const float*)d_in[9];
    const float* b1     = (const float*)d_in[10];
    const float* w2     = (const float*)d_in[11];
    const float* b2     = (const float*)d_in[12];
    const float* w3     = (const float*)d_in[13];
    const float* b3     = (const float*)d_in[14];
    float* out = (float*)d_out;

    char* ws = (char*)d_ws;
    float* inv1 = (float*)ws;                                    // 262144 f
    float* inv2 = inv1 + (size_t)Bc * NF;                        // 262144 f
    float* VLp  = inv2 + (size_t)Bc * NF;                        // 1048576 f
    float* M2p  = VLp + (size_t)Bc * Tc * Hc * Rc * Dc;          // 32768 f
    float* S2p  = M2p + (size_t)Bc * Tc * Hc * Rc;               // 32768 f
    unsigned short* Lb  = (unsigned short*)(S2p + (size_t)Bc * Tc * Hc * Rc);
    unsigned short* XVb = Lb  + (size_t)TOK * 128;
    unsigned short* X2b = XVb + (size_t)TOK * 128;               // total ~198.3 MiB

    // Wcat (256x128 bf16) + bias (256 f) alias the VLp region (VL written later by k_land)
    unsigned short* Wcat = (unsigned short*)VLp;                 // 32768 us = 16384 f
    float* bias256 = VLp + 16384;

    // bf16 weight copies alias Lb (dead after k_out1)
    unsigned short* w1bf = Lb;
    unsigned short* w2bf = Lb + 65536;
    unsigned short* w3bf = Lb + 131072;

    k_rms_f32 <<<Bc * NF / 256, 256, 0, stream>>>(x, inv1);
    k_qk      <<<4,             256, 0, stream>>>(q_w, q_b, key_p, v_b, Wcat, bias256);
    k_cvt     <<<64,            256, 0, stream>>>(v_w, Wcat + 16384, 16384);
    k_projm   <<<TOK / 128,     256, 0, stream>>>(x, inv1, norm_w, Wcat, bias256, Lb, XVb);
    k_land    <<<Bc * Tc * Hc,  256, 0, stream>>>(Lb, XVb, VLp, M2p, S2p);
    k_out1    <<<TOK / 8,       256, 0, stream>>>(x, Lb, XVb, VLp, M2p, S2p, alpha, beta, X2b);
    k_cvt     <<<256, 256, 0, stream>>>(w1, w1bf, 65536);
    k_cvt     <<<256, 256, 0, stream>>>(w2, w2bf, 65536);
    k_cvt     <<<256, 256, 0, stream>>>(w3, w3bf, 65536);
    k_rms_bf16<<<Bc * NF / 256, 256, 0, stream>>>(X2b, inv2);
    k_ffn_mfma<<<Bc * Nc,       256, 0, stream>>>(X2b, inv2, norm_w, w1bf, b1, w2bf, b2, w3bf, b3, out);
}

// Round 6
// 592.559 us; speedup vs baseline: 4.5857x; 1.1682x over previous
//
#include <hip/hip_runtime.h>

#define DEV static __device__ __forceinline__

constexpr int Bc = 2, Tc = 128, Nc = 1024, Fc = 128, Hc = 4, Rc = 32, Dc = 32;
constexpr int NF  = Nc * Fc;        // 131072 = 2^17
constexpr int TOK = Bc * Tc * Nc;   // 262144
constexpr float EPSc = 1e-6f;
constexpr float RSD  = 0.17677669529663687f;  // 1/sqrt(32)

typedef __bf16 bf16x8 __attribute__((ext_vector_type(8)));
typedef float  f32x16 __attribute__((ext_vector_type(16)));
typedef unsigned short us8 __attribute__((ext_vector_type(8)));
typedef unsigned short us4 __attribute__((ext_vector_type(4)));

DEV unsigned short f2bu(float f) {              // fp32 -> bf16 (RNE)
    unsigned u = __builtin_bit_cast(unsigned, f);
    u += 0x7fffu + ((u >> 16) & 1u);
    return (unsigned short)(u >> 16);
}
DEV float bu2f(unsigned short s) {
    return __builtin_bit_cast(float, ((unsigned)s) << 16);
}
DEV float sigmoidf_(float z) { return 1.f / (1.f + __expf(-z)); }
DEV f32x16 zero16() { f32x16 z;
#pragma unroll
    for (int i = 0; i < 16; i++) z[i] = 0.f;
    return z; }

// ---------------- K1: rmsnorm-over-t scale factors (for x fp32) -----------------
__global__ void k_rms_f32(const float* __restrict__ x, float* __restrict__ inv) {
    int j = blockIdx.x * 256 + threadIdx.x;     // j = b*NF + p
    int b = j >> 17;
    int p = j & (NF - 1);
    const float* px = x + (size_t)b * Tc * NF + p;
    float s = 0.f;
#pragma unroll 8
    for (int t = 0; t < Tc; ++t) { float v = px[(size_t)t * NF]; s = fmaf(v, v, s); }
    inv[j] = rsqrtf(s * (1.f / Tc) + EPSc);
}

// ---------------- weight fp32 -> bf16 conversions ----------------
__global__ void k_cvt(const float* __restrict__ w, unsigned short* __restrict__ o, int n) {
    int i = blockIdx.x * 256 + threadIdx.x;
    if (i < n) o[i] = f2bu(w[i]);
}
__global__ void k_cvt3(const float* __restrict__ w1, const float* __restrict__ w2,
                       const float* __restrict__ w3, unsigned short* __restrict__ o) {
    int i = blockIdx.x * 256 + threadIdx.x;     // 196608 total
    float v;
    if (i < 65536)       v = w1[i];
    else if (i < 131072) v = w2[i - 65536];
    else                 v = w3[i - 131072];
    o[i] = f2bu(v);
}

// ---------------- K_qk: fold q_w and key_p into QK (128x128), + biases ----------------
__global__ void k_qk(const float* __restrict__ q_w, const float* __restrict__ q_b,
                     const float* __restrict__ key_p, const float* __restrict__ v_b,
                     unsigned short* __restrict__ Wcat, float* __restrict__ bias)
{
    __shared__ float sqw[32][128];   // [d][c] for this h
    __shared__ float skp[32][32];    // [r][d], pre-scaled by RSD
    int h = blockIdx.x, tid = threadIdx.x;
    for (int i = tid; i < 4096; i += 256) {
        int d = i >> 7, c = i & 127;
        sqw[d][c] = q_w[(size_t)(h * 32 + d) * 128 + c];
    }
    for (int i = tid; i < 1024; i += 256) {
        int r = i >> 5, d = i & 31;
        skp[r][d] = key_p[(size_t)(r * 4 + h) * 32 + d] * RSD;
    }
    __syncthreads();
    int r = tid >> 3;
    int c0 = (tid & 7) * 16;
    for (int cc = 0; cc < 16; ++cc) {
        int c = c0 + cc;
        float s = 0.f;
#pragma unroll
        for (int d = 0; d < 32; ++d) s = fmaf(sqw[d][c], skp[r][d], s);
        Wcat[(size_t)(h * 32 + r) * 128 + c] = f2bu(s);
    }
    if (tid < 32) {
        float s = 0.f;
#pragma unroll
        for (int d = 0; d < 32; ++d) s = fmaf(q_b[h * 32 + d], skp[tid][d], s);
        bias[h * 32 + tid] = s;
    }
    if (h == 0 && tid >= 64 && tid < 192) bias[128 + tid - 64] = v_b[tid - 64];
}

// ---------------- K2: MFMA projection: [L ; XV] = XN @ Wcat^T + bias ----------------
__global__ __launch_bounds__(256, 4) void k_projm(
    const float* __restrict__ x, const float* __restrict__ inv1, const float* __restrict__ nw,
    const unsigned short* __restrict__ Wcat, const float* __restrict__ bias,
    unsigned short* __restrict__ Lb, unsigned short* __restrict__ XVb)
{
    const int tid = threadIdx.x, lane = tid & 63, wv = tid >> 6;
    const int lr = lane & 31, lhi = lane >> 5;
    const int tokb = blockIdx.x * 128 + wv * 32;
    const int tok = tokb + lr;
    const int b = tok >> 17, n = tok & 1023;
    const float* px = x + (size_t)tok * 128;
    const float* pi = inv1 + (size_t)b * NF + n * 128;

    bf16x8 af[8];
#pragma unroll
    for (int s = 0; s < 8; ++s) {
        const int c0 = s * 16 + lhi * 8;
        float4 xa = *(const float4*)(px + c0);
        float4 xb = *(const float4*)(px + c0 + 4);
        float4 ia = *(const float4*)(pi + c0);
        float4 ib = *(const float4*)(pi + c0 + 4);
        float4 na = *(const float4*)(nw + c0);
        float4 nb = *(const float4*)(nw + c0 + 4);
        bf16x8 v;
        v[0] = (__bf16)(xa.x * ia.x * na.x);
        v[1] = (__bf16)(xa.y * ia.y * na.y);
        v[2] = (__bf16)(xa.z * ia.z * na.z);
        v[3] = (__bf16)(xa.w * ia.w * na.w);
        v[4] = (__bf16)(xb.x * ib.x * nb.x);
        v[5] = (__bf16)(xb.y * ib.y * nb.y);
        v[6] = (__bf16)(xb.z * ib.z * nb.z);
        v[7] = (__bf16)(xb.w * ib.w * nb.w);
        af[s] = v;
    }

#pragma unroll
    for (int ot = 0; ot < 8; ++ot) {
        const unsigned short* pw = Wcat + (size_t)(ot * 32 + lr) * 128 + lhi * 8;
        f32x16 acc = zero16();
#pragma unroll
        for (int s = 0; s < 8; ++s) {
            bf16x8 bw = *(const bf16x8*)(pw + s * 16);
            acc = __builtin_amdgcn_mfma_f32_32x32x16_bf16(af[s], bw, acc, 0, 0, 0);
        }
        const int o = ot * 32 + lr;
        const float bv = bias[o];
        unsigned short* dst = (ot < 4) ? Lb : XVb;
        const int oo = (ot < 4) ? o : o - 128;
#pragma unroll
        for (int r = 0; r < 16; ++r) {
            const int trow = tokb + (r & 3) + 8 * (r >> 2) + 4 * lhi;
            dst[(size_t)trow * 128 + oo] = f2bu(acc[r] + bv);
        }
    }
}

// ---------------- K3: landmark aggregation + n-softmax stats (parallel) ----------------
__global__ __launch_bounds__(256, 4) void k_land(
    const unsigned short* __restrict__ Lb, const unsigned short* __restrict__ XVb,
    float* __restrict__ VL, float* __restrict__ M2, float* __restrict__ S2)
{
    __shared__ float sL [64][33];
    __shared__ float sXV[64][36];
    __shared__ float redm[32][8];
    __shared__ float reds[32][8];
    int tid = threadIdx.x;
    int blk = blockIdx.x;               // bt*4 + h
    int h = blk & 3; int bt = blk >> 2;
    size_t base = (size_t)bt * Nc * 128 + h * 32;
    const int r_st = tid & 31, stripe = tid >> 5;     // stats mapping
    const int ti = tid >> 2, sub = tid & 3;           // p1 mapping
    const int r_acc = tid >> 3, d0 = (tid & 7) * 4;   // VL mapping
    float m_st = -1e30f, s_st = 0.f;
    float a0 = 0, a1 = 0, a2 = 0, a3 = 0;
    for (int n0 = 0; n0 < Nc; n0 += 64) {
        for (int k = tid; k < 2048; k += 256) {
            int i = k >> 5, rr = k & 31;
            size_t g = base + (size_t)(n0 + i) * 128 + rr;
            sL [i][rr] = bu2f(Lb [g]);
            sXV[i][rr] = bu2f(XVb[g]);
        }
        __syncthreads();
        // ---- online n-softmax stats: thread = (r, 8-token stripe) ----
#pragma unroll
        for (int i8 = 0; i8 < 8; ++i8) {
            float v = sL[stripe * 8 + i8][r_st];
            float mn = fmaxf(m_st, v);
            s_st = s_st * __expf(m_st - mn) + __expf(v - mn);
            m_st = mn;
        }
        // ---- p1 softmax over r: 4 threads per token, 8 r each ----
        float e[8];
        float mx = -1e30f;
#pragma unroll
        for (int j = 0; j < 8; ++j) mx = fmaxf(mx, sL[ti][sub * 8 + j]);
        mx = fmaxf(mx, __shfl_xor(mx, 1));
        mx = fmaxf(mx, __shfl_xor(mx, 2));
        float sm = 0.f;
#pragma unroll
        for (int j = 0; j < 8; ++j) { e[j] = __expf(sL[ti][sub * 8 + j] - mx); sm += e[j]; }
        sm += __shfl_xor(sm, 1);
        sm += __shfl_xor(sm, 2);
        float iv = 1.f / sm;
        __syncthreads();                 // all reads of sL done
#pragma unroll
        for (int j = 0; j < 8; ++j) sL[ti][sub * 8 + j] = e[j] * iv;
        __syncthreads();
        // ---- VL accumulate: thread = (r, 4 d) ----
#pragma unroll 2
        for (int i = 0; i < 64; ++i) {
            float p = sL[i][r_acc];
            float4 v = *(const float4*)&sXV[i][d0];
            a0 = fmaf(p, v.x, a0); a1 = fmaf(p, v.y, a1);
            a2 = fmaf(p, v.z, a2); a3 = fmaf(p, v.w, a3);
        }
        __syncthreads();
    }
    redm[r_st][stripe] = m_st;
    reds[r_st][stripe] = s_st;
    __syncthreads();
    if (tid < 32) {
        float m = -1e30f;
#pragma unroll
        for (int k = 0; k < 8; ++k) m = fmaxf(m, redm[tid][k]);
        float s = 0.f;
#pragma unroll
        for (int k = 0; k < 8; ++k) s += reds[tid][k] * __expf(redm[tid][k] - m);
        M2[blk * 32 + tid] = m;
        S2[blk * 32 + tid] = s;
    }
    *(float4*)&VL[((size_t)blk * 32 + r_acc) * 32 + d0] = make_float4(a0, a1, a2, a3);
}

// ---------------- K4: scatter landmarks + gates + first residual ----------------
__global__ void k_out1(const float* __restrict__ x,
                       const unsigned short* __restrict__ Lb, const unsigned short* __restrict__ XVb,
                       const float* __restrict__ VL, const float* __restrict__ M2, const float* __restrict__ S2,
                       const float* __restrict__ alpha, const float* __restrict__ beta,
                       unsigned short* __restrict__ X2b)
{
    __shared__ float sVL[128][32];
    __shared__ float sP[8][128];
    __shared__ float sM[128], sSi[128], sAB[8];
    int tid = threadIdx.x;
    int tk0 = blockIdx.x * 8;
    int bt = tk0 >> 10;
    for (int k = tid; k < 4096; k += 256) sVL[k >> 5][k & 31] = VL[(size_t)bt * 4096 + k];
    if (tid < 128) { sM[tid] = M2[bt * 128 + tid]; sSi[tid] = 1.f / S2[bt * 128 + tid]; }
    if (tid < 8)   sAB[tid] = (tid < 4) ? sigmoidf_(alpha[tid]) : sigmoidf_(beta[tid - 4]);
    __syncthreads();
    for (int k = tid; k < 1024; k += 256) {
        int ti = k >> 7, f = k & 127;
        float lv = bu2f(Lb[(size_t)(tk0 + ti) * 128 + f]);
        sP[ti][f] = __expf(lv - sM[f]) * sSi[f];
    }
    __syncthreads();
    int ti = tid >> 5, quad = tid & 31;
    int h = quad >> 3, d0 = (quad & 7) * 4;
    float a0 = 0, a1 = 0, a2 = 0, a3 = 0;
    int hr0 = h * 32;
#pragma unroll 4
    for (int r = 0; r < 32; ++r) {
        float p = sP[ti][hr0 + r];
        float4 v = *(const float4*)&sVL[hr0 + r][d0];
        a0 = fmaf(p, v.x, a0); a1 = fmaf(p, v.y, a1);
        a2 = fmaf(p, v.z, a2); a3 = fmaf(p, v.w, a3);
    }
    size_t gi = (size_t)(tk0 + ti) * 128 + quad * 4;
    ushort4 xv4 = *(const ushort4*)&XVb[gi];
    float sa = sAB[h], sb = sAB[4 + h];
    float o0 = fmaf(sb, a0, fmaf(sa, bu2f(xv4.x), x[gi + 0]));
    float o1 = fmaf(sb, a1, fmaf(sa, bu2f(xv4.y), x[gi + 1]));
    float o2 = fmaf(sb, a2, fmaf(sa, bu2f(xv4.z), x[gi + 2]));
    float o3 = fmaf(sb, a3, fmaf(sa, bu2f(xv4.w), x[gi + 3]));
    ushort4 pk; pk.x = f2bu(o0); pk.y = f2bu(o1); pk.z = f2bu(o2); pk.w = f2bu(o3);
    *(ushort4*)&X2b[gi] = pk;
}

// ---------------- K6: MFMA FFN + fused rms2 + final residual ----------------
// block = (b,n), 4 waves. LDS stage of the 128t x 128f X2 slab (transposed,
// swizzled), in-kernel rmsnorm-over-t, double-buffered gT (1 barrier/iter).
constexpr int XST = 132;                 // xstage row stride (ushorts): 264B, 8B-aligned, 2-way banks
__global__ __launch_bounds__(256, 2) void k_ffn_mfma(
    const unsigned short* __restrict__ X2b, const float* __restrict__ nw,
    const unsigned short* __restrict__ w1b, const float* __restrict__ b1,
    const unsigned short* __restrict__ w2b, const float* __restrict__ b2,
    const unsigned short* __restrict__ w3b, const float* __restrict__ b3,
    float* __restrict__ out)
{
    __shared__ unsigned short smem[18432] __attribute__((aligned(16)));  // 36864 B union
    unsigned short* xstage = smem;           // [128][XST] = 16896 us
    unsigned short* gT     = smem;           // [2][128][72] = 18432 us
    __shared__ float sscale[128];

    const int tid  = threadIdx.x;
    const int lane = tid & 63;
    const int wv   = tid >> 6;
    const int lr   = lane & 31;
    const int lhi  = lane >> 5;
    const int blk  = blockIdx.x;
    const int b    = blk >> 10, n = blk & 1023;

    const int mrow = (wv & 1) * 32;     // o-local base (phase B)
    const int fh   = (wv >> 1) * 64;    // f base (phase B)
    const int t0   = wv * 32;           // t-tile base (phase C)

    // ---- stage X2 column-slab into LDS transposed: xstage[f][t ^ swz(f)] ----
    const unsigned short* xg = X2b + ((size_t)(b * Tc) * Nc + n) * 128;
#pragma unroll
    for (int p = 0; p < 8; ++p) {
        int i = p * 256 + tid;
        int t = i >> 4, fg = i & 15;
        us8 v = *(const us8*)(xg + (size_t)t * NF + fg * 8);
        int tt = t ^ ((fg & 7) << 3);
#pragma unroll
        for (int j = 0; j < 8; ++j) xstage[(fg * 8 + j) * XST + tt] = v[j];
    }
    __syncthreads();

    // ---- fused rms2: sum over t of X2^2 per f ----
    {
        int f = tid >> 1, half = tid & 1;
        int swz = ((f >> 3) & 7) << 3;
        float ss = 0.f;
#pragma unroll
        for (int kk = 0; kk < 8; ++kk) {
            int tb = (half * 64 + kk * 8) ^ swz;
            us4 u0 = *(const us4*)&xstage[f * XST + tb];
            us4 u1 = *(const us4*)&xstage[f * XST + tb + 4];
#pragma unroll
            for (int j = 0; j < 4; ++j) {
                float v0 = bu2f(u0[j]); ss = fmaf(v0, v0, ss);
                float v1 = bu2f(u1[j]); ss = fmaf(v1, v1, ss);
            }
        }
        ss += __shfl_xor(ss, 1);
        if (half == 0) sscale[f] = rsqrtf(ss * (1.f / Tc) + EPSc) * nw[f];
    }
    __syncthreads();

    // ---- build XN B-fragments from LDS ----
    bf16x8 xnf[2][8];
#pragma unroll
    for (int ft = 0; ft < 2; ++ft) {
        const int f = fh + ft * 32 + lr;
        const int swz = ((f >> 3) & 7) << 3;
        const float scale = sscale[f];
#pragma unroll
        for (int s = 0; s < 8; ++s) {
            int tb = (s * 16 + lhi * 8) ^ swz;
            us4 u0 = *(const us4*)&xstage[f * XST + tb];
            us4 u1 = *(const us4*)&xstage[f * XST + tb + 4];
            bf16x8 v;
#pragma unroll
            for (int j = 0; j < 4; ++j) {
                v[j]     = (__bf16)(bu2f(u0[j]) * scale);
                v[j + 4] = (__bf16)(bu2f(u1[j]) * scale);
            }
            xnf[ft][s] = v;
        }
    }
    __syncthreads();    // xstage dead; gT may now be written

    f32x16 oacc[4];
#pragma unroll
    for (int c = 0; c < 4; ++c) oacc[c] = zero16();

    const unsigned short* w1r = w1b + (size_t)(mrow + lr) * 128 + lhi * 8;
    const unsigned short* w2r = w2b + (size_t)(mrow + lr) * 128 + lhi * 8;
    const unsigned short* w3r = w3b + (size_t)(t0 + lr) * 512 + lhi * 8;

    int d = 0;
    for (int oc = 0; oc < 512; oc += 64) {
        // prefetch w3 fragments for this chunk (consumed after the barrier)
        bf16x8 a3[4];
        const unsigned short* pw3 = w3r + oc;
#pragma unroll
        for (int s = 0; s < 4; ++s) a3[s] = *(const bf16x8*)(pw3 + s * 16);

        // ---------- phase B: H1/H2 for this o-chunk ----------
        f32x16 h1a = zero16(), h1b = zero16(), h2a = zero16(), h2b = zero16();
        const unsigned short* pw1 = w1r + (size_t)oc * 128;
        const unsigned short* pw2 = w2r + (size_t)oc * 128;
#pragma unroll
        for (int s = 0; s < 8; ++s) {
            bf16x8 a1 = *(const bf16x8*)(pw1 + s * 16);
            bf16x8 a2 = *(const bf16x8*)(pw2 + s * 16);
            h1a = __builtin_amdgcn_mfma_f32_32x32x16_bf16(a1, xnf[0][s], h1a, 0, 0, 0);
            h1b = __builtin_amdgcn_mfma_f32_32x32x16_bf16(a1, xnf[1][s], h1b, 0, 0, 0);
            h2a = __builtin_amdgcn_mfma_f32_32x32x16_bf16(a2, xnf[0][s], h2a, 0, 0, 0);
            h2b = __builtin_amdgcn_mfma_f32_32x32x16_bf16(a2, xnf[1][s], h2b, 0, 0, 0);
        }
        // g = silu(h1 + b1) * (h2 + b2) -> gT[d]
        unsigned short* gTd = gT + d * 9216;
#pragma unroll
        for (int ft = 0; ft < 2; ++ft) {
            const int fcol = fh + ft * 32 + lr;
#pragma unroll
            for (int q = 0; q < 4; ++q) {
                ushort4 pk;
#pragma unroll
                for (int e = 0; e < 4; ++e) {
                    const int r = q * 4 + e;
                    const int orow = oc + mrow + e + 8 * q + 4 * lhi;
                    float z   = (ft ? h1b[r] : h1a[r]) + b1[orow];
                    float h2v = (ft ? h2b[r] : h2a[r]) + b2[orow];
                    float g   = z * sigmoidf_(z) * h2v;
                    unsigned short gb = f2bu(g);
                    if (e == 0) pk.x = gb; else if (e == 1) pk.y = gb;
                    else if (e == 2) pk.z = gb; else pk.w = gb;
                }
                const int o_l = mrow + 8 * q + 4 * lhi;
                *(ushort4*)&gTd[fcol * 72 + o_l] = pk;
            }
        }
        __syncthreads();
        // ---------- phase C: OUT += W3[:, oc..oc+63] * G ----------
#pragma unroll
        for (int s = 0; s < 4; ++s) {
#pragma unroll
            for (int c = 0; c < 4; ++c) {
                bf16x8 bg = *(const bf16x8*)&gTd[(c * 32 + lr) * 72 + s * 16 + lhi * 8];
                oacc[c] = __builtin_amdgcn_mfma_f32_32x32x16_bf16(a3[s], bg, oacc[c], 0, 0, 0);
            }
        }
        d ^= 1;   // next phase B writes the other buffer; no second barrier needed
    }

    // ---------- epilogue: out = acc + b3[t] + X2 ----------
#pragma unroll
    for (int r = 0; r < 16; ++r) {
        const int t = t0 + (r & 3) + 8 * (r >> 2) + 4 * lhi;
        const float bt3 = b3[t];
        const size_t rowbase = ((size_t)(b * Tc + t) * Nc + n) * 128;
#pragma unroll
        for (int c = 0; c < 4; ++c) {
            const int f = c * 32 + lr;
            const size_t gi = rowbase + f;
            out[gi] = oacc[c][r] + bt3 + bu2f(X2b[gi]);
        }
    }
}

extern "C" void kernel_launch(void* const* d_in, const int* in_sizes, int n_in,
                              void* d_out, int out_size, void* d_ws, size_t ws_size,
                              hipStream_t stream) {
    const float* x      = (const float*)d_in[0];
    const float* norm_w = (const float*)d_in[1];
    const float* q_w    = (const float*)d_in[2];
    const float* q_b    = (const float*)d_in[3];
    const float* key_p  = (const float*)d_in[4];
    const float* v_w    = (const float*)d_in[5];
    const float* v_b    = (const float*)d_in[6];
    const float* alpha  = (const float*)d_in[7];
    const float* beta   = (const float*)d_in[8];
    const float* w1     = (const float*)d_in[9];
    const float* b1     = (const float*)d_in[10];
    const float* w2     = (const float*)d_in[11];
    const float* b2     = (const float*)d_in[12];
    const float* w3     = (const float*)d_in[13];
    const float* b3     = (const float*)d_in[14];
    float* out = (float*)d_out;

    char* ws = (char*)d_ws;
    float* inv1 = (float*)ws;                                    // 262144 f
    float* inv2 = inv1 + (size_t)Bc * NF;                        // 262144 f (unused now)
    float* VLp  = inv2 + (size_t)Bc * NF;                        // 1048576 f
    float* M2p  = VLp + (size_t)Bc * Tc * Hc * Rc * Dc;          // 32768 f
    float* S2p  = M2p + (size_t)Bc * Tc * Hc * Rc;               // 32768 f
    unsigned short* Lb  = (unsigned short*)(S2p + (size_t)Bc * Tc * Hc * Rc);
    unsigned short* XVb = Lb  + (size_t)TOK * 128;
    unsigned short* X2b = XVb + (size_t)TOK * 128;               // total ~198.3 MiB

    // Wcat (256x128 bf16) + bias (256 f) alias the VLp region (VL written later by k_land)
    unsigned short* Wcat = (unsigned short*)VLp;                 // 32768 us = 16384 f
    float* bias256 = VLp + 16384;

    // bf16 weight copies alias Lb (dead after k_out1)
    unsigned short* w1bf = Lb;
    unsigned short* w2bf = Lb + 65536;
    unsigned short* w3bf = Lb + 131072;

    k_rms_f32 <<<Bc * NF / 256, 256, 0, stream>>>(x, inv1);
    k_qk      <<<4,             256, 0, stream>>>(q_w, q_b, key_p, v_b, Wcat, bias256);
    k_cvt     <<<64,            256, 0, stream>>>(v_w, Wcat + 16384, 16384);
    k_projm   <<<TOK / 128,     256, 0, stream>>>(x, inv1, norm_w, Wcat, bias256, Lb, XVb);
    k_land    <<<Bc * Tc * Hc,  256, 0, stream>>>(Lb, XVb, VLp, M2p, S2p);
    k_out1    <<<TOK / 8,       256, 0, stream>>>(x, Lb, XVb, VLp, M2p, S2p, alpha, beta, X2b);
    k_cvt3    <<<768,           256, 0, stream>>>(w1, w2, w3, w1bf);
    k_ffn_mfma<<<Bc * Nc,       256, 0, stream>>>(X2b, norm_w, w1bf, b1, w2bf, b2, w3bf, b3, out);
}